// Round 10
// baseline (117.132 us; speedup 1.0000x reference)
//
#include <hip/hip_runtime.h>

// MorphClassifier: out[i] = wrap8(trunc(max(|x[i,0]+b0|, |x[i,1]+b1|)))
// Memory-bound: 64 MiB in + 32 MiB out -> ~15 us floor at 6.3 TB/s.
//
// R10 = RETRY of the R3-R9 measurement round (all hit GPUAcquisitionTimeout;
// never ran). Kernel body is byte-identical to R2; we launch it TWICE
// (idempotent, deterministic). dur_us(R10) - dur_us(R2=102.5us) ~= kernel's
// own (L3-hot) duration, which the top-5 profile cutoff hides. This
// disambiguates "kernel at stream floor + ~67us fixed harness resets in
// dur_us" from "kernel is secretly slow".

__global__ __launch_bounds__(256) void morph_kernel(
    const float4* __restrict__ x4,     // B/2 float4 (each = 2 rows of x[B,2])
    const float* __restrict__ biases,  // [2]
    float2* __restrict__ out2,         // B/2 float2
    int n)                             // B/2
{
    const float b0 = biases[0];
    const float b1 = biases[1];
    const int stride = gridDim.x * blockDim.x;
    for (int i = blockIdx.x * blockDim.x + threadIdx.x; i < n; i += stride) {
        const float4 p = x4[i];
        // rows: (p.x,p.y) and (p.z,p.w)
        const float m0 = fmaxf(fabsf(p.x + b0), fabsf(p.y + b1));
        const float m1 = fmaxf(fabsf(p.z + b0), fabsf(p.w + b1));
        // m >= 0 always (max over a and -a), so (int) == trunc and
        // ((vi+128) % 256) - 128 == ((vi+128) & 255) - 128.
        float2 r;
        r.x = (float)((((int)m0 + 128) & 255) - 128);
        r.y = (float)((((int)m1 + 128) & 255) - 128);
        out2[i] = r;
    }
}

extern "C" void kernel_launch(void* const* d_in, const int* in_sizes, int n_in,
                              void* d_out, int out_size, void* d_ws, size_t ws_size,
                              hipStream_t stream) {
    const float4* x4     = (const float4*)d_in[0];   // [B,2] f32 -> B/2 float4
    const float*  biases = (const float*)d_in[1];    // [2]
    // d_in[2] (weights) and d_in[3] (threshold) are unused by the reference.
    float2* out2 = (float2*)d_out;

    const int n = out_size / 2;  // B/2 = 4194304
    const int block = 256;
    int grid = (n + block - 1) / block;
    if (grid > 2048) grid = 2048;  // grid-stride (8 iters/thread)

    // Launch TWICE for the A/B timing probe (see header comment).
    morph_kernel<<<grid, block, 0, stream>>>(x4, biases, out2, n);
    morph_kernel<<<grid, block, 0, stream>>>(x4, biases, out2, n);
}

// Round 11
// 101.776 us; speedup vs baseline: 1.1509x; 1.1509x over previous
//
#include <hip/hip_runtime.h>

// MorphClassifier: out[i] = wrap8(trunc(max(|x[i,0]+b0|, |x[i,1]+b1|)))
// Memory-bound: 64 MiB in + 32 MiB out -> 15.2 us floor at 6.3 TB/s.
//
// R11 = FINAL: revert to single launch after the R10 double-launch probe
// measured the kernel's own (L3-hot) time at 14.65 us (117.13 - 102.48),
// i.e. ~6.55 TB/s effective — at the HBM stream ceiling. The remaining
// ~87 us of dur_us is fixed harness reset traffic (256 MiB ws-poison @42us
// + out-poison + input restore), not kernel-addressable.
//
// Layout: each thread loads ONE contiguous float4 (16B/lane, ideal
// coalescing) = 2 rows of x[B,2], stores one float2 (8B/lane).

__global__ __launch_bounds__(256) void morph_kernel(
    const float4* __restrict__ x4,     // B/2 float4 (each = 2 rows of x[B,2])
    const float* __restrict__ biases,  // [2]
    float2* __restrict__ out2,         // B/2 float2
    int n)                             // B/2
{
    const float b0 = biases[0];
    const float b1 = biases[1];
    const int stride = gridDim.x * blockDim.x;
    for (int i = blockIdx.x * blockDim.x + threadIdx.x; i < n; i += stride) {
        const float4 p = x4[i];
        // rows: (p.x,p.y) and (p.z,p.w)
        const float m0 = fmaxf(fabsf(p.x + b0), fabsf(p.y + b1));
        const float m1 = fmaxf(fabsf(p.z + b0), fabsf(p.w + b1));
        // m >= 0 always (max over a and -a), so (int) == trunc and
        // ((vi+128) % 256) - 128 == ((vi+128) & 255) - 128.
        float2 r;
        r.x = (float)((((int)m0 + 128) & 255) - 128);
        r.y = (float)((((int)m1 + 128) & 255) - 128);
        out2[i] = r;
    }
}

extern "C" void kernel_launch(void* const* d_in, const int* in_sizes, int n_in,
                              void* d_out, int out_size, void* d_ws, size_t ws_size,
                              hipStream_t stream) {
    const float4* x4     = (const float4*)d_in[0];   // [B,2] f32 -> B/2 float4
    const float*  biases = (const float*)d_in[1];    // [2]
    // d_in[2] (weights) and d_in[3] (threshold) are unused by the reference.
    float2* out2 = (float2*)d_out;

    const int n = out_size / 2;  // B/2 = 4194304
    const int block = 256;
    int grid = (n + block - 1) / block;
    if (grid > 2048) grid = 2048;  // grid-stride (8 iters/thread)

    morph_kernel<<<grid, block, 0, stream>>>(x4, biases, out2, n);
}